// Round 1
// baseline (1050.530 us; speedup 1.0000x reference)
//
#include <hip/hip_runtime.h>
#include <math.h>

// Problem constants (match reference)
#define Bb   256
#define Tt   512
#define Vv   50000
#define Ee   300
#define Hh   128
#define G4   512          // 4*H
#define EPS  1e-12f
#define FBIAS 1.0f

struct F2 { float x, y; };
__device__ inline void fma2(F2& a, const F2 b, const float s) {
    a.x = fmaf(b.x, s, a.x);
    a.y = fmaf(b.y, s, a.y);
}

// ---------------------------------------------------------------------------
// Phase 1: P[v, :] = embed[v, :] @ W[0:E, :]   (V x 4H = 50000 x 512)
// Block computes a 32-row x 512-col tile. embed tile staged in LDS
// transposed (a[k][r]) so the inner loop reads it with broadcast float4.
// Thread t owns columns (2t, 2t+1).
// ---------------------------------------------------------------------------
__global__ __launch_bounds__(256) void embed_proj_kernel(
    const float* __restrict__ embed,   // [V, E]
    const float* __restrict__ W,       // [E+H, 4H]
    float* __restrict__ P)             // [V, 4H]
{
    __shared__ __align__(16) float a[Ee * 32];   // a[k*32 + r], 38.4 KB
    const int r0 = blockIdx.x * 32;
    const int t  = threadIdx.x;

    // Stage embed rows r0..r0+31 (transposed into LDS)
    for (int i = t; i < 32 * Ee; i += 256) {
        int r = i / Ee;
        int k = i - r * Ee;
        int row = r0 + r;
        a[k * 32 + r] = (row < Vv) ? embed[(size_t)row * Ee + k] : 0.0f;
    }
    __syncthreads();

    F2 acc[32];
    #pragma unroll
    for (int r = 0; r < 32; ++r) { acc[r].x = 0.f; acc[r].y = 0.f; }

    const float* wcol = W + 2 * t;   // column pair base
    for (int k = 0; k < Ee; ++k) {
        F2 bv = *(const F2*)(wcol + (size_t)k * G4);
        const float* ak = &a[k * 32];
        #pragma unroll
        for (int r4 = 0; r4 < 32; r4 += 4) {
            float4 av = *(const float4*)(ak + r4);
            fma2(acc[r4 + 0], bv, av.x);
            fma2(acc[r4 + 1], bv, av.y);
            fma2(acc[r4 + 2], bv, av.z);
            fma2(acc[r4 + 3], bv, av.w);
        }
    }

    #pragma unroll
    for (int r = 0; r < 32; ++r) {
        int row = r0 + r;
        if (row < Vv) {
            *(F2*)&P[(size_t)row * G4 + 2 * t] = acc[r];
        }
    }
}

// ---------------------------------------------------------------------------
// Phase 2: sequential LSTM. One block per batch row, 512 threads (8 waves).
// Thread t owns output column t of z = P[x_t] + h @ Wh.
// Wh column t (128 floats) lives in registers for the whole T loop.
// Waves 0-3 do the 4 gate layer-norms; threads 0-127 do the cell update.
// ---------------------------------------------------------------------------
__global__ __launch_bounds__(512, 2) void lstm_seq_kernel(
    const float* __restrict__ P,       // [V, 4H]
    const float* __restrict__ W,       // [E+H, 4H] (rows E.. are Wh)
    const int*   __restrict__ x,       // [B, T]
    const float* __restrict__ gains,   // [5, H]
    const float* __restrict__ shifts,  // [5, H]
    float* __restrict__ out)           // [B, T, H]
{
    const int b = blockIdx.x;
    const int t = threadIdx.x;          // 0..511
    const int w_id = t >> 6;            // wave id 0..7
    const int l    = t & 63;            // lane id

    __shared__ __align__(16) float h_lds[Hh];
    __shared__ __align__(16) float z_lds[G4];
    __shared__ float red[8];
    __shared__ int   xrow[Tt];

    // Load Wh column t into registers: w[k] = W[(E+k)*4H + t]
    float w[Hh];
    #pragma unroll
    for (int k = 0; k < Hh; ++k) {
        w[k] = W[(size_t)(Ee + k) * G4 + t];
    }

    // Preload LN params for my roles
    float gA = 0.f, gB = 0.f, sA = 0.f, sB = 0.f;   // gate-LN (waves 0..3)
    if (w_id < 4) {
        gA = gains[w_id * Hh + l];
        gB = gains[w_id * Hh + 64 + l];
        sA = shifts[w_id * Hh + l];
        sB = shifts[w_id * Hh + 64 + l];
    }
    float gc = 0.f, sc = 0.f;                        // cell-LN (threads 0..127)
    if (t < Hh) {
        gc = gains[4 * Hh + t];
        sc = shifts[4 * Hh + t];
    }

    // Stage this row's token ids; init state
    xrow[t] = x[(size_t)b * Tt + t];
    if (t < Hh) h_lds[t] = 0.f;
    float c = 0.f;                                   // cell state (threads 0..127)
    __syncthreads();

    for (int step = 0; step < Tt; ++step) {
        // Prefetch the embedding-projection contribution (L3-resident)
        const int row = xrow[step];
        const float pz = P[(size_t)row * G4 + t];

        // GEMV: acc = h . Wh[:, t]
        float acc0 = 0.f, acc1 = 0.f;
        #pragma unroll
        for (int k = 0; k < Hh; k += 4) {
            float4 hh = *(const float4*)&h_lds[k];
            acc0 = fmaf(hh.x, w[k + 0], acc0);
            acc1 = fmaf(hh.y, w[k + 1], acc1);
            acc0 = fmaf(hh.z, w[k + 2], acc0);
            acc1 = fmaf(hh.w, w[k + 3], acc1);
        }
        z_lds[t] = pz + acc0 + acc1;
        __syncthreads();   // B1: z staged

        // Gate layer-norms: wave g handles gate g over its 128 values
        if (w_id < 4) {
            float v0 = z_lds[w_id * Hh + l];
            float v1 = z_lds[w_id * Hh + 64 + l];
            float s = v0 + v1;
            float q = v0 * v0 + v1 * v1;
            #pragma unroll
            for (int off = 32; off > 0; off >>= 1) {
                s += __shfl_xor(s, off);
                q += __shfl_xor(q, off);
            }
            float mean = s * (1.0f / Hh);
            float var  = q * (1.0f / Hh) - mean * mean;
            float rstd = rsqrtf(var + EPS);
            z_lds[w_id * Hh + l]      = (v0 - mean) * rstd * gA + sA;
            z_lds[w_id * Hh + 64 + l] = (v1 - mean) * rstd * gB + sB;
        }
        __syncthreads();   // B2: normalized gates ready

        // Cell update: threads 0..127, hdim = t
        float ov = 0.f;
        if (t < Hh) {
            float iv = z_lds[t];
            float jv = z_lds[Hh + t];
            float fv = z_lds[2 * Hh + t];
            ov       = z_lds[3 * Hh + t];
            float g  = fmaxf(jv, 0.f);
            float si = 1.f / (1.f + __expf(-iv));
            float sf = 1.f / (1.f + __expf(-(fv + FBIAS)));
            c = c * sf + si * g;

            // LN over new_c across threads 0..127 (waves 0 and 1)
            float s = c, q = c * c;
            #pragma unroll
            for (int off = 32; off > 0; off >>= 1) {
                s += __shfl_xor(s, off);
                q += __shfl_xor(q, off);
            }
            if (l == 0) { red[w_id * 2] = s; red[w_id * 2 + 1] = q; }
        }
        __syncthreads();   // B3: cell-LN partials ready

        if (t < Hh) {
            float s = red[0] + red[2];
            float q = red[1] + red[3];
            float mean = s * (1.0f / Hh);
            float var  = q * (1.0f / Hh) - mean * mean;
            float lc   = (c - mean) * rsqrtf(var + EPS) * gc + sc;
            float so   = 1.f / (1.f + __expf(-ov));
            float hn   = fmaxf(lc, 0.f) * so;
            h_lds[t] = hn;
            out[((size_t)b * Tt + step) * Hh + t] = hn;
        }
        __syncthreads();   // B4: h ready for next step
    }
}

// ---------------------------------------------------------------------------
extern "C" void kernel_launch(void* const* d_in, const int* in_sizes, int n_in,
                              void* d_out, int out_size, void* d_ws, size_t ws_size,
                              hipStream_t stream) {
    const int*   x      = (const int*)d_in[0];
    const float* embed  = (const float*)d_in[1];
    const float* W      = (const float*)d_in[2];
    const float* gains  = (const float*)d_in[3];
    const float* shifts = (const float*)d_in[4];
    float* out = (float*)d_out;

    // Workspace: P = embed @ W[0:E,:]  -> 50000 * 512 floats = 102.4 MB
    float* P = (float*)d_ws;

    embed_proj_kernel<<<dim3((Vv + 31) / 32), dim3(256), 0, stream>>>(embed, W, P);
    lstm_seq_kernel<<<dim3(Bb), dim3(512), 0, stream>>>(P, W, x, gains, shifts, out);
}

// Round 3
// 903.185 us; speedup vs baseline: 1.1631x; 1.1631x over previous
//
#include <hip/hip_runtime.h>
#include <math.h>

// Problem constants (match reference)
#define Bb   256
#define Tt   512
#define Vv   50000
#define Ee   300
#define Hh   128
#define G4   512          // 4*H
#define EPS  1e-12f
#define FBIAS 1.0f
#define RPB  4            // batch rows per block (phase 2)
#define NBLK (Bb / RPB)   // 64 blocks

typedef _Float16 half8 __attribute__((ext_vector_type(8)));
typedef float    f32x4 __attribute__((ext_vector_type(4)));

struct F2 { float x, y; };
__device__ inline void fma2(F2& a, const F2 b, const float s) {
    a.x = fmaf(b.x, s, a.x);
    a.y = fmaf(b.y, s, a.y);
}

// ---------------------------------------------------------------------------
// Phase 1: P[v, :] = embed[v, :] @ W[0:E, :]
// ---------------------------------------------------------------------------
__global__ __launch_bounds__(256) void embed_proj_kernel(
    const float* __restrict__ embed,   // [V, E]
    const float* __restrict__ W,       // [E+H, 4H]
    float* __restrict__ P)             // [V, 4H]
{
    __shared__ __align__(16) float a[Ee * 32];   // a[k*32 + r]
    const int r0 = blockIdx.x * 32;
    const int t  = threadIdx.x;

    for (int i = t; i < 32 * Ee; i += 256) {
        int r = i / Ee;
        int k = i - r * Ee;
        int row = r0 + r;
        a[k * 32 + r] = (row < Vv) ? embed[(size_t)row * Ee + k] : 0.0f;
    }
    __syncthreads();

    F2 acc[32];
    #pragma unroll
    for (int r = 0; r < 32; ++r) { acc[r].x = 0.f; acc[r].y = 0.f; }

    const float* wcol = W + 2 * t;
    for (int k = 0; k < Ee; ++k) {
        F2 bv = *(const F2*)(wcol + (size_t)k * G4);
        const float* ak = &a[k * 32];
        #pragma unroll
        for (int r4 = 0; r4 < 32; r4 += 4) {
            float4 av = *(const float4*)(ak + r4);
            fma2(acc[r4 + 0], bv, av.x);
            fma2(acc[r4 + 1], bv, av.y);
            fma2(acc[r4 + 2], bv, av.z);
            fma2(acc[r4 + 3], bv, av.w);
        }
    }

    #pragma unroll
    for (int r = 0; r < 32; ++r) {
        int row = r0 + r;
        if (row < Vv) {
            *(F2*)&P[(size_t)row * G4 + 2 * t] = acc[r];
        }
    }
}

// ---------------------------------------------------------------------------
// Cross-lane helpers
// ---------------------------------------------------------------------------
template <int CTRL>
__device__ inline float dpp_mov(float v) {
    return __int_as_float(
        __builtin_amdgcn_update_dpp(0, __float_as_int(v), CTRL, 0xF, 0xF, true));
}
// sum over each 16-lane group
__device__ inline float red16(float v) {
    v += dpp_mov<0xB1>(v);    // quad_perm [1,0,3,2]
    v += dpp_mov<0x4E>(v);    // quad_perm [2,3,0,1]
    v += dpp_mov<0x141>(v);   // row_half_mirror
    v += dpp_mov<0x140>(v);   // row_mirror
    return v;
}
// sum over all 64 lanes
__device__ inline float red64(float v, int bp_addr) {
    v = red16(v);
    v += __int_as_float(__builtin_amdgcn_ds_swizzle(__float_as_int(v), 0x401F)); // xor16
    v += __int_as_float(__builtin_amdgcn_ds_bpermute(bp_addr, __float_as_int(v))); // xor32
    return v;
}

// barrier that drains only LDS counters (vmcnt prefetches float across)
__device__ inline void lds_barrier() {
    __builtin_amdgcn_sched_barrier(0);
    asm volatile("s_waitcnt lgkmcnt(0)" ::: "memory");
    __builtin_amdgcn_sched_barrier(0);
    __builtin_amdgcn_s_barrier();
    __builtin_amdgcn_sched_barrier(0);
}

__device__ inline float sigm(float v) {
    return __fdividef(1.0f, 1.0f + __expf(-v));
}

// ---------------------------------------------------------------------------
// Phase 2: 64 blocks x 4 batch rows, 256 threads (4 waves).
//  - Wh (f16) lives in registers as MFMA B-fragments (wave w owns gate w's
//    128 columns = 8 coltiles x 4 ksteps).
//  - h is an f16 [16][128] LDS tile (rows 4..15 stay zero), XOR-swizzled.
//  - per step: MFMA z = h @ Wh -> z_lds[4][512]; barrier; per-row wave does
//    LN (16-lane DPP reduce) + cell update + cell-LN (64-lane reduce);
//    barrier.
//  - P[x[r,t]] contribution prefetched to registers one step ahead.
// ---------------------------------------------------------------------------
__global__ __launch_bounds__(256, 1) void lstm_mfma_kernel(
    const float* __restrict__ P,       // [V, 4H]
    const float* __restrict__ W,       // [E+H, 4H]
    const int*   __restrict__ x,       // [B, T]
    const float* __restrict__ gains,   // [5, H]
    const float* __restrict__ shifts,  // [5, H]
    float* __restrict__ out)           // [B, T, H]
{
    __shared__ __align__(16) float    z_lds[RPB][G4];      // 8 KB
    __shared__ __align__(16) float    zn[4][4][Hh];        // 8 KB per-wave scratch
    __shared__ __align__(16) _Float16 h_lds[16][Hh];       // 4 KB (swizzled)

    const int tid  = threadIdx.x;
    const int wv   = tid >> 6;         // wave id 0..3 (= gate in MFMA, = row in LN)
    const int lane = tid & 63;
    const int bb   = blockIdx.x;

    const int gq   = lane >> 4;        // gate handled by this lane in LN phase
    const int p16  = lane & 15;
    const int col8 = lane * 8;         // == gq*128 + p16*8, cols owned in LN phase
    const int bp_addr = ((lane ^ 32) << 2);

    // ---- zero h_lds (rows 4..15 stay zero forever) ----
    {
        uint* hz = (uint*)h_lds;
        #pragma unroll
        for (int i = 0; i < 4; ++i) hz[tid + 256 * i] = 0u;
    }

    // ---- preload Wh as f16 B-fragments: bfrag[tt][ks], wave wv -> gate wv ----
    half8 bfrag[8][4];
    {
        const int bcol = wv * 128 + p16;
        const int kro  = gq * 8;       // (lane>>4)*8 k-offset within kstep
        #pragma unroll
        for (int tt = 0; tt < 8; ++tt) {
            #pragma unroll
            for (int ks = 0; ks < 4; ++ks) {
                half8 h;
                #pragma unroll
                for (int j = 0; j < 8; ++j) {
                    h[j] = (_Float16)W[(size_t)(Ee + ks * 32 + kro + j) * G4 + bcol + tt * 16];
                }
                bfrag[tt][ks] = h;
            }
        }
    }

    // ---- preload LN params ----
    const float4 g_a = *(const float4*)&gains[col8];
    const float4 g_b = *(const float4*)&gains[col8 + 4];
    const float4 s_a = *(const float4*)&shifts[col8];
    const float4 s_b = *(const float4*)&shifts[col8 + 4];
    const float2 gcell = *(const float2*)&gains[4 * Hh + 2 * lane];
    const float2 scell = *(const float2*)&shifts[4 * Hh + 2 * lane];

    const int row_g = bb * RPB + wv;          // global batch row for this wave
    const int* xrow = x + (size_t)row_g * Tt;

    // cell state for hdims (2*lane, 2*lane+1) of row wv
    float c0 = 0.f, c1 = 0.f;

    // prologue: prefetch P for step 0
    int tok = xrow[0];
    float4 pc0 = *(const float4*)&P[(size_t)tok * G4 + col8];
    float4 pc1 = *(const float4*)&P[(size_t)tok * G4 + col8 + 4];

    char* const hb = (char*)h_lds;
    const int arow = p16;                       // A-row this lane reads
    const int asw  = (arow & 7) << 4;           // XOR swizzle bits
    const int kc16 = gq << 4;                   // (lane>>4)*16 byte chunk

    __syncthreads();

    for (int t = 0; t < Tt; ++t) {
        // ---------------- Phase A: prefetch + MFMA + stage z ----------------
        int tn = (t + 1 < Tt) ? t + 1 : Tt - 1;
        int tokn = xrow[tn];
        float4 pn0 = *(const float4*)&P[(size_t)tokn * G4 + col8];
        float4 pn1 = *(const float4*)&P[(size_t)tokn * G4 + col8 + 4];

        half8 af[4];
        #pragma unroll
        for (int ks = 0; ks < 4; ++ks) {
            af[ks] = *(const half8*)(hb + arow * 256 + ((ks * 64 + kc16) ^ asw));
        }

        f32x4 acc[8];
        #pragma unroll
        for (int tt = 0; tt < 8; ++tt) acc[tt] = (f32x4){0.f, 0.f, 0.f, 0.f};
        #pragma unroll
        for (int tt = 0; tt < 8; ++tt) {
            #pragma unroll
            for (int ks = 0; ks < 4; ++ks) {
                acc[tt] = __builtin_amdgcn_mfma_f32_16x16x32_f16(
                    af[ks], bfrag[tt][ks], acc[tt], 0, 0, 0);
            }
        }

        if (lane < 16) {
            #pragma unroll
            for (int tt = 0; tt < 8; ++tt) {
                const int col = wv * 128 + tt * 16 + lane;
                #pragma unroll
                for (int r = 0; r < 4; ++r) z_lds[r][col] = acc[tt][r];
            }
        }

        lds_barrier();   // B1: z staged (vmcnt not drained)

        // ---------------- Phase B: LN + cell for row wv ----------------
        float zv[8];
        {
            float4 za = *(const float4*)&z_lds[wv][col8];
            float4 zb = *(const float4*)&z_lds[wv][col8 + 4];
            zv[0] = za.x + pc0.x; zv[1] = za.y + pc0.y;
            zv[2] = za.z + pc0.z; zv[3] = za.w + pc0.w;
            zv[4] = zb.x + pc1.x; zv[5] = zb.y + pc1.y;
            zv[6] = zb.z + pc1.z; zv[7] = zb.w + pc1.w;
        }

        // gate-LN: reduce over this gate's 128 cols (16 lanes x 8 each)
        float s = 0.f, q = 0.f;
        #pragma unroll
        for (int j = 0; j < 8; ++j) { s += zv[j]; q = fmaf(zv[j], zv[j], q); }
        s = red16(s); q = red16(q);
        {
            const float mean = s * (1.0f / Hh);
            const float var  = q * (1.0f / Hh) - mean * mean;
            const float rstd = rsqrtf(var + EPS);
            const float ga[8] = {g_a.x, g_a.y, g_a.z, g_a.w, g_b.x, g_b.y, g_b.z, g_b.w};
            const float sa[8] = {s_a.x, s_a.y, s_a.z, s_a.w, s_b.x, s_b.y, s_b.z, s_b.w};
            #pragma unroll
            for (int j = 0; j < 8; ++j)
                zv[j] = (zv[j] - mean) * rstd * ga[j] + sa[j];
        }

        // transpose through per-wave scratch (same-wave LDS, in-order, no barrier)
        *(float4*)&zn[wv][gq][p16 * 8]     = (float4){zv[0], zv[1], zv[2], zv[3]};
        *(float4*)&zn[wv][gq][p16 * 8 + 4] = (float4){zv[4], zv[5], zv[6], zv[7]};

        float2 iv = *(const float2*)&zn[wv][0][2 * lane];
        float2 jv = *(const float2*)&zn[wv][1][2 * lane];
        float2 fv = *(const float2*)&zn[wv][2][2 * lane];
        float2 ov = *(const float2*)&zn[wv][3][2 * lane];

        // cell update for hdims 2*lane, 2*lane+1
        c0 = c0 * sigm(fv.x + FBIAS) + sigm(iv.x) * fmaxf(jv.x, 0.f);
        c1 = c1 * sigm(fv.y + FBIAS) + sigm(iv.y) * fmaxf(jv.y, 0.f);

        // cell-LN over 128 hdims (full wave)
        float s2 = c0 + c1;
        float q2 = fmaf(c0, c0, c1 * c1);
        s2 = red64(s2, bp_addr); q2 = red64(q2, bp_addr);
        const float m2 = s2 * (1.0f / Hh);
        const float v2 = q2 * (1.0f / Hh) - m2 * m2;
        const float r2 = rsqrtf(v2 + EPS);
        const float lc0 = (c0 - m2) * r2 * gcell.x + scell.x;
        const float lc1 = (c1 - m2) * r2 * gcell.y + scell.y;
        const float h0 = fmaxf(lc0, 0.f) * sigm(ov.x);
        const float h1 = fmaxf(lc1, 0.f) * sigm(ov.y);

        // store h (f16, swizzled) + output (f32)
        {
            union { _Float16 hh[2]; uint u; } pk;
            pk.hh[0] = (_Float16)h0; pk.hh[1] = (_Float16)h1;
            *(uint*)(hb + wv * 256 + ((4 * lane) ^ (wv << 4))) = pk.u;
        }
        *(float2*)&out[((size_t)row_g * Tt + t) * Hh + 2 * lane] = (float2){h0, h1};

        lds_barrier();   // B2: h ready, z_lds free

        pc0 = pn0; pc1 = pn1;
    }
}

// ---------------------------------------------------------------------------
extern "C" void kernel_launch(void* const* d_in, const int* in_sizes, int n_in,
                              void* d_out, int out_size, void* d_ws, size_t ws_size,
                              hipStream_t stream) {
    const int*   x      = (const int*)d_in[0];
    const float* embed  = (const float*)d_in[1];
    const float* W      = (const float*)d_in[2];
    const float* gains  = (const float*)d_in[3];
    const float* shifts = (const float*)d_in[4];
    float* out = (float*)d_out;

    float* P = (float*)d_ws;   // [V, 4H] = 102.4 MB

    embed_proj_kernel<<<dim3((Vv + 31) / 32), dim3(256), 0, stream>>>(embed, W, P);
    lstm_mfma_kernel<<<dim3(NBLK), dim3(256), 0, stream>>>(P, W, x, gains, shifts, out);
}